// Round 8
// baseline (25072.560 us; speedup 1.0000x reference)
//
#include <hip/hip_runtime.h>
#include <hip/hip_bf16.h>

#define TSTEPS 4096
#define XD 256
#define HD 2048
#define YD 256
#define KD 2304   // XD + HD
#define NWG 256
#define NT 512

// ---- LDS layout (bytes) ----
#define WU_OFF 0
#define WR_OFF (8*KD*2)            // 36864
#define WC_OFF (16*KD*2)           // 73728
#define WY_OFF (24*KD*2)           // 110592
#define V1_OFF (WY_OFF + HD*4)     // 118784  v1 = [x_t | h_{t-1}]
#define V2_OFF (V1_OFF + KD*4)     // 128000  v2 = [x_t | r]
#define RED_OFF (V2_OFF + KD*4)    // 137216  red: u[8], yp[8], bu[8], br[8], bc[8], by
#define LDS_BYTES (RED_OFF + 256)  // 137472

// ---- workspace ----
// go lines (zeroed) + 4 sentinel-armed exchange buffers (0x7F).
// |h|<=1, |r|<=1 provably (tanh/sigmoid bounds, h0=0) -> 0x7F7F7F7F is
// unreachable -> safe sentinel. Data IS the flag for the MASTER only
// (512 pollers grid-wide = R2-scale, no storm); consumers gather post-go.
#define GOH_U32 0                  // 8 lines x 128B
#define GOR_U32 256
#define GO_BYTES 2048
#define HB0_OFF 2048
#define HB1_OFF 10240
#define RB0_OFF 18432
#define RB1_OFF 26624
#define ARM_BYTES 32768
#define SENT32 0x7F7F7F7Fu

__device__ __forceinline__ float bflo(unsigned u){ return __uint_as_float(u << 16); }
__device__ __forceinline__ float bfhi(unsigned u){ return __uint_as_float(u & 0xffff0000u); }
__device__ __forceinline__ unsigned short f2bf(float f){
  unsigned b = __float_as_uint(f);
  b += 0x7fffu + ((b >> 16) & 1u);   // RTNE (inputs finite)
  return (unsigned short)(b >> 16);
}
__device__ __forceinline__ float sigmoidf_(float x){ return 1.0f / (1.0f + __expf(-x)); }

__device__ __forceinline__ void gst32f(float* p, float v){
  __hip_atomic_store(p, v, __ATOMIC_RELAXED, __HIP_MEMORY_SCOPE_AGENT);
}
__device__ __forceinline__ void flagst(unsigned* p, unsigned v){
  __hip_atomic_store(p, v, __ATOMIC_RELAXED, __HIP_MEMORY_SCOPE_AGENT);
}
// Sleepless go spin: 255 tid0s over 8 lines (<=32/line), reissue ~every RTT.
__device__ __forceinline__ void spinflag(const unsigned* p, unsigned epoch, long* budget){
  while (__hip_atomic_load(p, __ATOMIC_RELAXED, __HIP_MEMORY_SCOPE_AGENT) < epoch) {
    if (--(*budget) < 0) break;     // anti-hang: proceed rather than deadlock
  }
}

// AGENT-scope coalesced 16B load (sc1 only = LLC-serviced; sc0+sc1 would be
// system scope -> HBM RTT, R4's regression).
__device__ __forceinline__ float4 cohload16(const float4* p){
  float4 r;
  asm volatile("global_load_dwordx4 %0, %1, off sc1\n\t"
               "s_waitcnt vmcnt(0)"
               : "=v"(r) : "v"(p) : "memory");
  return r;
}
__device__ __forceinline__ int has_sent(float4 v){
  return (__float_as_uint(v.x) == SENT32) | (__float_as_uint(v.y) == SENT32) |
         (__float_as_uint(v.z) == SENT32) | (__float_as_uint(v.w) == SENT32);
}
// Master-only data poll: hard spin on my own 16B slice until non-sentinel.
__device__ __forceinline__ float4 pollslice(const float4* p, long* budget){
  float4 v = cohload16(p);
  while (has_sent(v)) {
    if (--(*budget) < 0) break;
    v = cohload16(p);
  }
  return v;
}
// Re-arm my 8-float slice (32B) with sentinel (drained by the next
// cohload16's inline vmcnt(0) before any later publish -> master can never
// see stale non-sentinel data).
__device__ __forceinline__ void reset_slice(float* gbuf, int col0, int tid){
  if (tid < 2) {
    unsigned long long s = 0x7F7F7F7F7F7F7F7FULL;
    unsigned long long* p = (unsigned long long*)(gbuf + col0) + 2*tid;
    __hip_atomic_store(p,     s, __ATOMIC_RELAXED, __HIP_MEMORY_SCOPE_AGENT);
    __hip_atomic_store(p + 1, s, __ATOMIC_RELAXED, __HIP_MEMORY_SCOPE_AGENT);
  }
}

template<int I0, int I1, int STRIDE>
__device__ __forceinline__ void dotacc(const float* v, const unsigned short* wcol,
                                       int lane, float4& acc){
  #pragma unroll
  for (int i = I0; i < I1; ++i) {
    int k = 4 * (lane + STRIDE * i);
    float4 vv = *(const float4*)(v + k);
    uint2  wq = *(const uint2*)(wcol + k);
    acc.x = fmaf(vv.x, bflo(wq.x), acc.x);
    acc.y = fmaf(vv.y, bfhi(wq.x), acc.y);
    acc.z = fmaf(vv.z, bflo(wq.y), acc.z);
    acc.w = fmaf(vv.w, bfhi(wq.y), acc.w);
  }
}

extern "C" __global__ void __launch_bounds__(NT)
gru_persistent(const float* __restrict__ x,  const float* __restrict__ h0,
               const float* __restrict__ Wc, const float* __restrict__ Wu,
               const float* __restrict__ Wr, const float* __restrict__ bc,
               const float* __restrict__ bu, const float* __restrict__ br,
               const float* __restrict__ Wy, const float* __restrict__ by,
               float* __restrict__ out, unsigned* wsu)
{
  extern __shared__ char smem[];
  unsigned short* wuS = (unsigned short*)(smem + WU_OFF);
  unsigned short* wrS = (unsigned short*)(smem + WR_OFF);
  unsigned short* wcS = (unsigned short*)(smem + WC_OFF);
  float* wyS = (float*)(smem + WY_OFF);
  float* v1  = (float*)(smem + V1_OFF);
  float* v2  = (float*)(smem + V2_OFF);
  float* red = (float*)(smem + RED_OFF);

  unsigned* goh = wsu + GOH_U32;
  unsigned* gor = wsu + GOR_U32;
  float* hb[2] = { (float*)((char*)wsu + HB0_OFF), (float*)((char*)wsu + HB1_OFF) };
  float* rb[2] = { (float*)((char*)wsu + RB0_OFF), (float*)((char*)wsu + RB1_OFF) };

  const int wg = blockIdx.x, tid = threadIdx.x;
  const int col0 = 8 * wg;

  // ---- one-time weight staging: WG j owns gate cols [8j,8j+8), y col j ----
  for (int idx = tid; idx < 8*KD; idx += NT) {
    int c = idx & 7, k = idx >> 3;
    size_t g = (size_t)k * HD + col0 + c;   // W is [KD, 2048] row-major
    wuS[c*KD + k] = f2bf(Wu[g]);
    wrS[c*KD + k] = f2bf(Wr[g]);
    wcS[c*KD + k] = f2bf(Wc[g]);
  }
  for (int k = tid; k < HD; k += NT) wyS[k] = Wy[(size_t)k * YD + wg];
  if (tid < 8) {
    red[16+tid] = bu[col0+tid];
    red[24+tid] = br[col0+tid];
    red[32+tid] = bc[col0+tid];
  }
  if (tid == 0) red[40] = by[wg];
  __syncthreads();

  long budget = 20000000;   // spin cap (~few s worst), then bail (no hang)

  float4 xpref = make_float4(0.f, 0.f, 0.f, 0.f);
  if (tid < XD/4) xpref = ((const float4*)x)[tid];

  const int hw = tid >> 5, l = tid & 31, c = hw & 7;   // phase-1 mapping
  const int w  = tid >> 6, l6 = tid & 63;              // phase-2 / y mapping
  const unsigned short* wcol = ((hw < 8) ? wuS : wrS) + c * KD;
  const unsigned short* ccol = wcS + w * KD;

  for (int t = 0; t < TSTEPS; ++t) {
    float4 a1 = make_float4(0.f, 0.f, 0.f, 0.f);

    // ================= H EXCHANGE =================
    if (t == 0) {
      if (tid < XD/4) { ((float4*)v1)[tid] = xpref; ((float4*)v2)[tid] = xpref; }
      ((float4*)(v1 + XD))[tid] = ((const float4*)h0)[tid];
      __syncthreads();
      dotacc<0, 2, 32>(v1, wcol, l, a1);
    } else if (wg == 0) {
      // master: data-poll IS certification + gather in one
      float4 hv = pollslice((const float4*)hb[(t+1)&1] + tid, &budget);
      ((float4*)(v1 + XD))[tid] = hv;
      __syncthreads();                                  // all slices confirmed
      if (tid < 8) flagst(goh + tid*32, (unsigned)t);
      if (tid < XD/4) { ((float4*)v1)[tid] = xpref; ((float4*)v2)[tid] = xpref; }
      __syncthreads();
      dotacc<0, 2, 32>(v1, wcol, l, a1);                // hidden under consumers' catch-up
      if (t) reset_slice(rb[(t+1)&1], col0, tid);
    } else {
      // consumer: x work hidden under the go wait
      if (tid < XD/4) { ((float4*)v1)[tid] = xpref; ((float4*)v2)[tid] = xpref; }
      __syncthreads();
      dotacc<0, 2, 32>(v1, wcol, l, a1);
      if (tid == 0) spinflag(goh + (wg & 7)*32, (unsigned)t, &budget);
      __syncthreads();
      float4 hv = cohload16((const float4*)hb[(t+1)&1] + tid);   // certified
      ((float4*)(v1 + XD))[tid] = hv;
      __syncthreads();
      reset_slice(rb[(t+1)&1], col0, tid);   // h certified => r_{t-1} consumed
    }

    // ---- phase 1 h-part: Lu (half-waves 0-7), Lr (8-15) ----
    dotacc<2, 18, 32>(v1, wcol, l, a1);
    {
      float s = (a1.x + a1.y) + (a1.z + a1.w);
      s += __shfl_xor(s, 16); s += __shfl_xor(s, 8); s += __shfl_xor(s, 4);
      s += __shfl_xor(s, 2);  s += __shfl_xor(s, 1);
      if (l == 0) {
        if (hw < 8) red[c] = sigmoidf_(s + red[16+c]);                              // u gate
        else gst32f(rb[t&1] + col0 + c, sigmoidf_(s + red[24+c]) * v1[XD+col0+c]);  // r*h (no flag!)
      }
    }

    // ================= R EXCHANGE =================
    float4 a2 = make_float4(0.f, 0.f, 0.f, 0.f);
    if (wg == 0) {
      float4 rv = pollslice((const float4*)rb[t&1] + tid, &budget);
      ((float4*)(v2 + XD))[tid] = rv;
      __syncthreads();
      if (tid < 8) flagst(gor + tid*32, (unsigned)(t+1));
      // master's hidden work AFTER go (consumers are catching up)
      {
        int k = 256 * w + 4 * l6;
        float4 hv  = *(const float4*)(v1 + XD + k);
        float4 wy4 = *(const float4*)(wyS + k);
        float ys = fmaf(hv.x, wy4.x, fmaf(hv.y, wy4.y, fmaf(hv.z, wy4.z, hv.w * wy4.w)));
        ys += __shfl_xor(ys, 32); ys += __shfl_xor(ys, 16); ys += __shfl_xor(ys, 8);
        ys += __shfl_xor(ys, 4);  ys += __shfl_xor(ys, 2);  ys += __shfl_xor(ys, 1);
        if (l6 == 0) red[8 + w] = ys;
      }
      dotacc<0, 1, 64>(v2, ccol, l6, a2);               // phase-2 x-part
      if (tid < XD/4 && t + 1 < TSTEPS)
        xpref = ((const float4*)(x + (size_t)(t+1) * XD))[tid];
      __syncthreads();
    } else {
      // consumer hidden work BEFORE the wait
      {
        int k = 256 * w + 4 * l6;
        float4 hv  = *(const float4*)(v1 + XD + k);
        float4 wy4 = *(const float4*)(wyS + k);
        float ys = fmaf(hv.x, wy4.x, fmaf(hv.y, wy4.y, fmaf(hv.z, wy4.z, hv.w * wy4.w)));
        ys += __shfl_xor(ys, 32); ys += __shfl_xor(ys, 16); ys += __shfl_xor(ys, 8);
        ys += __shfl_xor(ys, 4);  ys += __shfl_xor(ys, 2);  ys += __shfl_xor(ys, 1);
        if (l6 == 0) red[8 + w] = ys;
      }
      dotacc<0, 1, 64>(v2, ccol, l6, a2);               // phase-2 x-part
      if (tid < XD/4 && t + 1 < TSTEPS)
        xpref = ((const float4*)(x + (size_t)(t+1) * XD))[tid];
      if (tid == 0) spinflag(gor + (wg & 7)*32, (unsigned)(t+1), &budget);
      __syncthreads();
      float4 rv = cohload16((const float4*)rb[t&1] + tid);   // certified
      ((float4*)(v2 + XD))[tid] = rv;
      __syncthreads();
    }
    if (t) reset_slice(hb[(t+1)&1], col0, tid);   // r_t certified => h_{t-1} consumed
    if (tid == 0 && t > 0) {
      float y = red[8]+red[9]+red[10]+red[11]+red[12]+red[13]+red[14]+red[15] + red[40];
      out[(size_t)(t-1) * YD + wg] = y;           // fire-and-forget
    }

    // ---- phase 2: candidate (wave w -> col w), h⊙r part ----
    dotacc<1, 9, 64>(v2, ccol, l6, a2);
    {
      float s = (a2.x + a2.y) + (a2.z + a2.w);
      s += __shfl_xor(s, 32); s += __shfl_xor(s, 16); s += __shfl_xor(s, 8);
      s += __shfl_xor(s, 4);  s += __shfl_xor(s, 2);  s += __shfl_xor(s, 1);
      if (l6 == 0) {
        float cc = tanhf(s + red[32 + w]);
        float u  = red[w];
        float hp = v1[XD + col0 + w];
        gst32f(hb[t&1] + col0 + w, cc * u + hp * (1.0f - u));  // h_t (no flag!)
      }
    }
    __syncthreads();   // protects v1/v2/red rewrite next iteration
  }

  // ---- epilogue: final h exchange (epoch TSTEPS), y[T-1], h_fin ----
  if (wg == 0) {
    float4 hv = pollslice((const float4*)hb[(TSTEPS-1)&1] + tid, &budget);
    ((float4*)(v1 + XD))[tid] = hv;
    __syncthreads();
    if (tid < 8) flagst(goh + tid*32, (unsigned)TSTEPS);
  } else {
    if (tid == 0) spinflag(goh + (wg & 7)*32, (unsigned)TSTEPS, &budget);
    __syncthreads();
    float4 hv = cohload16((const float4*)hb[(TSTEPS-1)&1] + tid);
    ((float4*)(v1 + XD))[tid] = hv;
  }
  __syncthreads();
  {
    int k = 256 * w + 4 * l6;
    float4 hv  = *(const float4*)(v1 + XD + k);
    float4 wy4 = *(const float4*)(wyS + k);
    float ys = fmaf(hv.x, wy4.x, fmaf(hv.y, wy4.y, fmaf(hv.z, wy4.z, hv.w * wy4.w)));
    ys += __shfl_xor(ys, 32); ys += __shfl_xor(ys, 16); ys += __shfl_xor(ys, 8);
    ys += __shfl_xor(ys, 4);  ys += __shfl_xor(ys, 2);  ys += __shfl_xor(ys, 1);
    if (l6 == 0) red[8 + w] = ys;
  }
  __syncthreads();
  if (tid == 0) {
    float y = red[8]+red[9]+red[10]+red[11]+red[12]+red[13]+red[14]+red[15] + red[40];
    out[(size_t)(TSTEPS-1) * YD + wg] = y;
  }
  if (tid < 8) out[(size_t)TSTEPS * YD + col0 + tid] = v1[XD + col0 + tid];
}

extern "C" void kernel_launch(void* const* d_in, const int* in_sizes, int n_in,
                              void* d_out, int out_size, void* d_ws, size_t ws_size,
                              hipStream_t stream) {
  const float* x  = (const float*)d_in[0];
  const float* h0 = (const float*)d_in[1];
  const float* Wc = (const float*)d_in[2];
  const float* Wu = (const float*)d_in[3];
  const float* Wr = (const float*)d_in[4];
  const float* bc = (const float*)d_in[5];
  const float* bu = (const float*)d_in[6];
  const float* br = (const float*)d_in[7];
  const float* Wy = (const float*)d_in[8];
  const float* by = (const float*)d_in[9];
  float* out = (float*)d_out;
  unsigned* wsu = (unsigned*)d_ws;

  // >64 KB dynamic LDS on gfx950 (160 KB/CU). Idempotent; capture-safe.
  hipFuncSetAttribute((const void*)gru_persistent,
                      hipFuncAttributeMaxDynamicSharedMemorySize, LDS_BYTES);
  hipMemsetAsync(d_ws, 0, GO_BYTES, stream);                          // go epochs = 0
  hipMemsetAsync((char*)d_ws + GO_BYTES, 0x7F, ARM_BYTES, stream);    // arm sentinels
  gru_persistent<<<dim3(NWG), dim3(NT), LDS_BYTES, stream>>>(
      x, h0, Wc, Wu, Wr, bc, bu, br, Wy, by, out, wsu);
}